// Round 14
// baseline (232.551 us; speedup 1.0000x reference)
//
#include <hip/hip_runtime.h>
#include <math.h>

#define H 4
#define SEQ 610
#define BATCH 128
// 2-tick per-layer handoff: layer l (= wave l) computes timestep t = tau - 2*l.
#define NITER 619
#define HEAD 16
#define TAIL0 616

typedef float v2f __attribute__((ext_vector_type(2)));

#if __has_builtin(__builtin_elementwise_fma)
#define FMA2(a, b, c) __builtin_elementwise_fma((a), (b), (c))
#else
static __device__ __forceinline__ v2f FMA2(v2f a, v2f b, v2f c) {
    v2f r; r[0] = fmaf(a[0], b[0], c[0]); r[1] = fmaf(a[1], b[1], c[1]); return r;
}
#endif
static __device__ __forceinline__ v2f splat2(float a) { v2f r; r[0] = a; r[1] = a; return r; }

// update_dpp with explicit row/bank masks. quad_perm 0x00/0x55/0xAA/0xFF,
// row_shl:4 0x104, row_shr:4 0x114. Masked-out lanes keep `old`.
template<int CTRL, int RM, int BM, bool BC>
__device__ __forceinline__ float dppm(float old_, float src) {
    return __int_as_float(__builtin_amdgcn_update_dpp(
        __float_as_int(old_), __float_as_int(src), CTRL, RM, BM, BC));
}

// One block = one batch row, 5 waves = 5 layers (wavefront-pipelined over time,
// 2-tick skew). Within a wave, lanes 0-7 carry the layer: lane = j2*4+k,
// j2 = gate-pair {i,f}/{g,o}, k = hidden unit (R13 pair layout, same algebra).
// Cross-layer handoff via LDS: producer writes its h-quad per tick (b32,
// per-lane), consumer broadcast-reads it (b128) one tick later with 2-tick
// algebraic slack; 4-slot rotation + per-tick __syncthreads().
__global__ __launch_bounds__(320) void lstm_mw_kernel(
    const float* __restrict__ x,      // [128,610,2]
    const float* __restrict__ w_ih0,  // [16,2]
    const float* __restrict__ w_ih,   // [4,16,4]
    const float* __restrict__ w_hh,   // [5,16,4]
    const float* __restrict__ b_ih,   // [5,16]
    const float* __restrict__ b_hh,   // [5,16]
    const float* __restrict__ w_lin,  // [1,4]
    const float* __restrict__ b_lin,  // [1]
    const float* __restrict__ w_fc,   // [5,610]
    const float* __restrict__ b_fc,   // [5]
    float* __restrict__ out)          // [128,5]
{
    __shared__ __align__(16) float lds_x4[(SEQ + 12) * 4];   // [t]{x0,x1,0,0}
    __shared__ __align__(16) float lds_wfcp[4 * SEQ * 2 + 8];// [4][610][2]={wfc[k],wfc[4]}
    __shared__ __align__(16) float lds_h[5][4][64];          // [layer][slot][lane]

    const int tid  = threadIdx.x;
    const int w    = tid >> 6;        // wave id = layer id (0..4)
    const int lane = tid & 63;
    const int j2   = (lane >> 2) & 1;
    const int k    = lane & 3;
    const int b    = blockIdx.x;

    // ---- zero x4 pad + h slots ----
    for (int i = tid; i < (SEQ + 12) * 4; i += 320) lds_x4[i] = 0.f;
    for (int i = tid; i < 5 * 4 * 64; i += 320) ((float*)lds_h)[i] = 0.f;
    __syncthreads();
    // ---- stage x (as {x0,x1,0,0} quads) and paired w_fc ----
    for (int t = tid; t < SEQ; t += 320) {
        const float2 xv = *(const float2*)&x[(size_t)b * (SEQ * 2) + t * 2];
        lds_x4[t * 4 + 0] = xv.x;
        lds_x4[t * 4 + 1] = xv.y;   // components 2,3 stay 0
    }
    #pragma unroll
    for (int kk = 0; kk < 4; ++kk) {
        for (int t = tid; t < SEQ; t += 320) {
            lds_wfcp[(kk * SEQ + t) * 2 + 0] = w_fc[kk * SEQ + t];
            lds_wfcp[(kk * SEQ + t) * 2 + 1] = w_fc[4 * SEQ + t];
        }
    }
    __syncthreads();

    // ---- per-lane weights: gate pair {2j2, 2j2+1} of unit k, layer w ----
    v2f wip[4], whp[4], bp;
    {
        const int ga = 2 * j2, gb = ga + 1;
        const float sa = (ga == 2) ? 2.8853900817779268f   // +2*log2(e) for g
                                   : -1.4426950408889634f; // -log2(e) for i,f,o
        const float sb = -1.4426950408889634f;             // f or o
        const int ra = ga * H + k, rb = gb * H + k;
        #pragma unroll
        for (int m = 0; m < 4; ++m) {
            float wa, wb;
            if (w == 0) {
                wa = (m < 2) ? w_ih0[ra * 2 + m] : 0.f;
                wb = (m < 2) ? w_ih0[rb * 2 + m] : 0.f;
            } else {
                wa = w_ih[((w - 1) * 16 + ra) * 4 + m];
                wb = w_ih[((w - 1) * 16 + rb) * 4 + m];
            }
            wip[m][0] = wa * sa; wip[m][1] = wb * sb;
            whp[m][0] = w_hh[(w * 16 + ra) * 4 + m] * sa;
            whp[m][1] = w_hh[(w * 16 + rb) * 4 + m] * sb;
        }
        bp[0] = (b_ih[w * 16 + ra] + b_hh[w * 16 + ra]) * sa;
        bp[1] = (b_ih[w * 16 + rb] + b_hh[w * 16 + rb]) * sb;
    }
    const float wl0 = w_lin[0], wl1 = w_lin[1], wl2 = w_lin[2], wl3 = w_lin[3];
    const float bl  = b_lin[0];
    const int wpbase = k * SEQ;

    // xin source for tick tau+1's pre (chain(tau+1) input h_{w-1}(tau-1)):
    //   w==0: x(tau+1) quad; w>0: lds_h[w-1][(tau-1)&3]  ((tau+3)&3 avoids neg)
    #define XIN_PTR(tau_) ((w == 0) ? (const float4*)&lds_x4[((tau_) + 1) * 4] \
                                    : (const float4*)&lds_h[w - 1][((tau_) + 3) & 3][0])

    // ---- state ----
    float c = 0.f;
    float q0 = 0.f, q1 = 0.f, q2 = 0.f, q3 = 0.f;   // own-layer h(tau-1) quad
    v2f acc2 = splat2(0.f);
    v2f pre;                                         // chain(0) pre-activation
    {
        float xs0 = 0.f, xs1 = 0.f;
        if (w == 0) { xs0 = lds_x4[0]; xs1 = lds_x4[1]; }   // x(0); else h(-2)=0
        pre = FMA2(wip[1], splat2(xs1), FMA2(wip[0], splat2(xs0), bp));
    }

    #define TICK(tau_, GATED)                                                         \
    {                                                                                 \
        /* loads issued at tick top; consumed ~chain-length later */                  \
        const float4 xn = *XIN_PTR(tau_);                                             \
        int t4 = (tau_) - 9;                                                          \
        if (GATED) t4 = t4 < 0 ? 0 : t4;                                              \
        const float2 wv = *(const float2*)&lds_wfcp[(wpbase + t4) * 2];               \
        const float oq0 = q0, oq1 = q1, oq2 = q2, oq3 = q3;                           \
        /* ---- CHAIN (identical algebra to R13) ---- */                              \
        v2f G = FMA2(whp[3], splat2(oq3), FMA2(whp[2], splat2(oq2),                   \
                FMA2(whp[1], splat2(oq1), FMA2(whp[0], splat2(oq0), pre))));          \
        v2f A; A[0] = 1.f + __builtin_amdgcn_exp2f(G[0]);                             \
        A[1] = 1.f + __builtin_amdgcn_exp2f(G[1]);                                    \
        float X0, X1, Y0, Y1;   /* X={Ai,Af}, Y={Dg,Ao} on lanes 0-7 */               \
        X0 = dppm<0x114, 0xF, 0xA, false>(A[0], A[0]);                                \
        X1 = dppm<0x114, 0xF, 0xA, false>(A[1], A[1]);                                \
        Y0 = dppm<0x104, 0xF, 0x5, false>(A[0], A[0]);                                \
        Y1 = dppm<0x104, 0xF, 0x5, false>(A[1], A[1]);                                \
        const float M   = X0 * Y0;                                                    \
        const float den = M * X1;                                                     \
        const float num = fmaf(c, M, X1 * (Y0 - 2.f));                                \
        float cn = num * __builtin_amdgcn_rcpf(den);                                  \
        if (GATED) { const unsigned tt = (unsigned)((tau_) - 2 * w);                  \
                     cn = (tt < SEQ) ? cn : 0.f; }                                    \
        c = cn;                                                                       \
        const float Dc = 1.f + __builtin_amdgcn_exp2f(c * 2.8853900817779268f);       \
        const float hv = (Dc - 2.f) * __builtin_amdgcn_rcpf(Y1 * Dc);                 \
        /* publish h (per-lane b32, stride-1 banks; junk lanes write junk) */         \
        lds_h[w][(tau_) & 3][lane] = hv;                                              \
        /* own-quad gather for next tick's MAC */                                     \
        q0 = dppm<0x00, 0xF, 0xF, true>(0.f, hv);                                     \
        q1 = dppm<0x55, 0xF, 0xF, true>(0.f, hv);                                     \
        q2 = dppm<0xAA, 0xF, 0xF, true>(0.f, hv);                                     \
        q3 = dppm<0xFF, 0xF, 0xF, true>(0.f, hv);                                     \
        /* pre for chain(tau+1) from xn (off-chain) */                                \
        pre = FMA2(wip[3], splat2(xn.w), FMA2(wip[2], splat2(xn.z),                   \
              FMA2(wip[1], splat2(xn.y), FMA2(wip[0], splat2(xn.x), bp))));           \
        /* output head (meaningful on wave 4; junk elsewhere) */                      \
        float tval = fmaf(oq0, wl0, fmaf(oq1, wl1, fmaf(oq2, wl2, fmaf(oq3, wl3, bl)))); \
        if (GATED) tval = ((unsigned)((tau_) - 9) < SEQ) ? tval : 0.f;                \
        v2f wvv; wvv[0] = wv.x; wvv[1] = wv.y;                                        \
        acc2 = FMA2(splat2(tval), wvv, acc2);                                         \
        __syncthreads();                                                              \
    }

    // gated head: layers warm up (t<0 states forced to 0), acc gated
    for (int tau = 0; tau < HEAD; ++tau) TICK(tau, true);
    // clean body: junk timesteps (t>609) on layers 0-3 only ever feed junk
    // timesteps downstream (2-tick skew alignment), never a consumed value;
    // wfc index tau-9 in [7,606]; x reads stay inside padded lds_x4.
    #pragma unroll 2
    for (int tau = HEAD; tau < TAIL0; ++tau) TICK(tau, false);
    // gated tail: tval window ends at tau=618 (h4 of t=609); layer c gating benign
    for (int tau = TAIL0; tau < NITER; ++tau) TICK(tau, true);
    #undef TICK
    #undef XIN_PTR

    if (w == 4 && lane < 4) {
        out[b * 5 + k] = acc2[0] + b_fc[k];
        if (k == 0) out[b * 5 + 4] = acc2[1] + b_fc[4];
    }
}

extern "C" void kernel_launch(void* const* d_in, const int* in_sizes, int n_in,
                              void* d_out, int out_size, void* d_ws, size_t ws_size,
                              hipStream_t stream)
{
    const float* x     = (const float*)d_in[0];
    const float* w_ih0 = (const float*)d_in[1];
    const float* w_ih  = (const float*)d_in[2];
    const float* w_hh  = (const float*)d_in[3];
    const float* b_ih  = (const float*)d_in[4];
    const float* b_hh  = (const float*)d_in[5];
    const float* w_lin = (const float*)d_in[6];
    const float* b_lin = (const float*)d_in[7];
    const float* w_fc  = (const float*)d_in[8];
    const float* b_fc  = (const float*)d_in[9];
    float* out = (float*)d_out;

    lstm_mw_kernel<<<dim3(BATCH), dim3(320), 0, stream>>>(
        x, w_ih0, w_ih, w_hh, b_ih, b_hh, w_lin, b_lin, w_fc, b_fc, out);
}

// Round 15
// 159.069 us; speedup vs baseline: 1.4620x; 1.4620x over previous
//
#include <hip/hip_runtime.h>
#include <math.h>

#define H 4
#define NL 5
#define SEQ 610
#define BATCH 128
// 2-tick per-layer handoff: layer l computes timestep t = tau - 2*l.
#define NITER 619
#define HEAD 16      // gated head ticks
#define TAIL0 616    // HEAD + 75*8 ; ticks 616..618 are the gated tail

typedef float v2f __attribute__((ext_vector_type(2)));

#if __has_builtin(__builtin_elementwise_fma)
#define FMA2(a, b, c) __builtin_elementwise_fma((a), (b), (c))
#else
static __device__ __forceinline__ v2f FMA2(v2f a, v2f b, v2f c) {
    v2f r; r[0] = fmaf(a[0], b[0], c[0]); r[1] = fmaf(a[1], b[1], c[1]); return r;
}
#endif
static __device__ __forceinline__ v2f splat2(float a) { v2f r; r[0] = a; r[1] = a; return r; }

// update_dpp with explicit row/bank masks. quad_perm 0x00/0x55/0xAA/0xFF,
// row_shl:4 0x104, row_shr:4 0x114. Masked-out lanes keep `old`.
template<int CTRL, int RM, int BM, bool BC>
__device__ __forceinline__ float dppm(float old_, float src) {
    return __int_as_float(__builtin_amdgcn_update_dpp(
        __float_as_int(old_), __float_as_int(src), CTRL, RM, BM, BC));
}

// Lane layout (ONE batch row per wave, lanes 40-63 run a bounded phantom layer):
//   lane = l*8 + j2*4 + k ; layer l in lanes 8l..8l+7 (l=0..4).
//   j2 selects the gate PAIR: j2=0 -> {i,f}, j2=1 -> {g,o}; k = hidden unit.
// Cross-layer handoff: ds_bpermute lane-8 pull (1 instr/value, off-chain with
// ~250cy slack). Junk lanes (40-63) use clamped layer-4 weights and are fed by
// layer 4's output -> bounded finite dynamics, so wrapped bpermute sources for
// lanes 0-7 are finite; layer-0 consumers mask them (wip[2..3]=0, is_l0 selects).
__global__ __launch_bounds__(64) void lstm_bp_kernel(
    const float* __restrict__ x,      // [128,610,2]
    const float* __restrict__ w_ih0,  // [16,2]
    const float* __restrict__ w_ih,   // [4,16,4]
    const float* __restrict__ w_hh,   // [5,16,4]
    const float* __restrict__ b_ih,   // [5,16]
    const float* __restrict__ b_hh,   // [5,16]
    const float* __restrict__ w_lin,  // [1,4]
    const float* __restrict__ b_lin,  // [1]
    const float* __restrict__ w_fc,   // [5,610]
    const float* __restrict__ b_fc,   // [5]
    float* __restrict__ out)          // [128,5]
{
    __shared__ float lds_x[SEQ * 2 + 32];       // [610][2] + pad (tail over-reads)
    __shared__ float lds_wfcp[4 * SEQ * 2 + 8]; // [4][610][2] = {wfc[k][t], wfc[4][t]}

    const int lane  = threadIdx.x;
    const int l_raw = lane >> 3;
    const int l     = l_raw > 4 ? 4 : l_raw;   // clamp for weight loads (phantom layer)
    const int j2    = (lane >> 2) & 1;
    const int k     = lane & 3;
    const bool is_l0 = (l_raw == 0);
    const int b     = blockIdx.x;
    const int bpa   = ((lane - 8) & 63) * 4;   // bpermute byte addr: pull lane-8

    // ---- stage x row + paired w_fc into LDS, coalesced ----
    {
        const float4* src = (const float4*)(x + (size_t)b * (SEQ * 2));
        float4* dst = (float4*)lds_x;
        for (int i = lane; i < (SEQ * 2) / 4; i += 64) dst[i] = src[i];
    }
    #pragma unroll
    for (int kk = 0; kk < 4; ++kk) {
        for (int t = lane; t < SEQ; t += 64) {
            lds_wfcp[(kk * SEQ + t) * 2 + 0] = w_fc[kk * SEQ + t];
            lds_wfcp[(kk * SEQ + t) * 2 + 1] = w_fc[4 * SEQ + t];
        }
    }
    __syncthreads();

    // ---- per-lane weights: gate pair {ga,gb} = {2*j2, 2*j2+1} of unit k ----
    v2f wip[4], whp[4], bp;
    {
        const int ga = 2 * j2, gb = 2 * j2 + 1;
        const float sa = (ga == 2) ? 2.8853900817779268f : -1.4426950408889634f;
        const float sb = -1.4426950408889634f;  // gb is f (1) or o (3): always -log2e
        const int ra = ga * H + k, rb = gb * H + k;
        #pragma unroll
        for (int m = 0; m < 4; ++m) {
            float wa, wb;
            if (l == 0) {
                wa = (m < 2) ? w_ih0[ra * 2 + m] : 0.f;
                wb = (m < 2) ? w_ih0[rb * 2 + m] : 0.f;
            } else {
                wa = w_ih[((l - 1) * 16 + ra) * 4 + m];
                wb = w_ih[((l - 1) * 16 + rb) * 4 + m];
            }
            wip[m][0] = wa * sa; wip[m][1] = wb * sb;
            whp[m][0] = w_hh[(l * 16 + ra) * 4 + m] * sa;
            whp[m][1] = w_hh[(l * 16 + rb) * 4 + m] * sb;
        }
        bp[0] = (b_ih[l * 16 + ra] + b_hh[l * 16 + ra]) * sa;
        bp[1] = (b_ih[l * 16 + rb] + b_hh[l * 16 + rb]) * sb;
    }
    const float wl0 = w_lin[0], wl1 = w_lin[1], wl2 = w_lin[2], wl3 = w_lin[3];
    const float bl  = b_lin[0];
    const int wpbase = k * SEQ;

    // ---- state ----
    float c = 0.f;
    float q0 = 0.f, q1 = 0.f, q2 = 0.f, q3 = 0.f;  // h(tau-1), own layer, per-unit
    v2f acc2 = splat2(0.f);                         // {out[k]-acc, out[4]-acc}
    v2f pre;                                        // gate-pair pre-activation
    {
        const float2 xv0 = *(const float2*)&lds_x[0];
        const float xs0 = is_l0 ? xv0.x : 0.f;
        const float xs1 = is_l0 ? xv0.y : 0.f;
        pre = FMA2(wip[1], splat2(xs1), FMA2(wip[0], splat2(xs0), bp));
    }

    #define TICK_CORE(tau_, GATED, NXv, WVv)                                          \
    {                                                                                 \
        const float oq0 = q0, oq1 = q1, oq2 = q2, oq3 = q3;                           \
        /* ---- off-chain handoff: pull layer l-1's q (1 bpermute/value) ---- */      \
        const float p0 = __int_as_float(__builtin_amdgcn_ds_bpermute(bpa, __float_as_int(oq0))); \
        const float p1 = __int_as_float(__builtin_amdgcn_ds_bpermute(bpa, __float_as_int(oq1))); \
        const float p2 = __int_as_float(__builtin_amdgcn_ds_bpermute(bpa, __float_as_int(oq2))); \
        const float p3 = __int_as_float(__builtin_amdgcn_ds_bpermute(bpa, __float_as_int(oq3))); \
        /* ---- CHAIN: tree gates (depth 3) -> c -> h -> quad DPP ---- */             \
        v2f Ga = FMA2(whp[0], splat2(oq0), pre);                                      \
        v2f Gb = whp[3] * splat2(oq3);                                                \
        Ga = FMA2(whp[1], splat2(oq1), Ga);                                           \
        Gb = FMA2(whp[2], splat2(oq2), Gb);                                           \
        v2f G = Ga + Gb;                                                              \
        v2f A; A[0] = 1.f + __builtin_amdgcn_exp2f(G[0]);                             \
        A[1] = 1.f + __builtin_amdgcn_exp2f(G[1]);                                    \
        float X0, X1, Y0, Y1;   /* X={Ai,Af}, Y={Dg,Ao} on all lanes */               \
        X0 = dppm<0x114, 0xF, 0xA, false>(A[0], A[0]);                                \
        X1 = dppm<0x114, 0xF, 0xA, false>(A[1], A[1]);                                \
        Y0 = dppm<0x104, 0xF, 0x5, false>(A[0], A[0]);                                \
        Y1 = dppm<0x104, 0xF, 0x5, false>(A[1], A[1]);                                \
        const float M   = X0 * Y0;                                                    \
        const float den = M * X1;                                                     \
        const float num = fmaf(c, M, X1 * (Y0 - 2.f));                                \
        float cn = num * __builtin_amdgcn_rcpf(den);                                  \
        if (GATED) { const unsigned tt = (unsigned)((tau_) - 2 * l_raw);              \
                     cn = (tt < SEQ) ? cn : 0.f; }                                    \
        c = cn;                                                                       \
        const float Dc = 1.f + __builtin_amdgcn_exp2f(c * 2.8853900817779268f);       \
        const float hv = (Dc - 2.f) * __builtin_amdgcn_rcpf(Y1 * Dc);                 \
        q0 = dppm<0x00, 0xF, 0xF, true>(0.f, hv);                                     \
        q1 = dppm<0x55, 0xF, 0xF, true>(0.f, hv);                                     \
        q2 = dppm<0xAA, 0xF, 0xF, true>(0.f, hv);                                     \
        q3 = dppm<0xFF, 0xF, 0xF, true>(0.f, hv);                                     \
        /* ---- BURST: pre for next tick, output head ---- */                         \
        const float xs0 = is_l0 ? (NXv).x : p0;                                       \
        const float xs1 = is_l0 ? (NXv).y : p1;                                       \
        pre = FMA2(wip[3], splat2(p3), FMA2(wip[2], splat2(p2),                       \
              FMA2(wip[1], splat2(xs1), FMA2(wip[0], splat2(xs0), bp))));             \
        float tval = fmaf(oq0, wl0, fmaf(oq1, wl1, fmaf(oq2, wl2, fmaf(oq3, wl3, bl)))); \
        if (GATED) tval = ((unsigned)((tau_) - 9) < SEQ) ? tval : 0.f;                \
        v2f wvv; wvv[0] = (WVv).x; wvv[1] = (WVv).y;                                  \
        acc2 = FMA2(splat2(tval), wvv, acc2);                                         \
    }

    // ---- gated head: per-tick LDS loads, clamped indices ----
    for (int tau = 0; tau < HEAD; ++tau) {
        const float2 nx = *(const float2*)&lds_x[(tau + 1) * 2];
        int t4 = tau - 9; t4 = t4 < 0 ? 0 : t4;
        const float2 wv = *(const float2*)&lds_wfcp[(wpbase + t4) * 2];
        TICK_CORE(tau, true, nx, wv);
    }

    // ---- clean body: 75 chunks x 8 ticks; loads batched per chunk into regs.
    // Junk timesteps (t>609) on layers 0-3 cannot reach layer-4's consumed h
    // before the loop ends; wfc index tau-9 stays in [7,606]; x over-reads stay
    // inside the padded lds_x.
    for (int ch = 0; ch < 75; ++ch) {
        const int tau0 = HEAD + ch * 8;
        float2 xc_[8], wc_[8];
        #pragma unroll
        for (int i = 0; i < 8; ++i) {
            xc_[i] = *(const float2*)&lds_x[(tau0 + 1 + i) * 2];
            wc_[i] = *(const float2*)&lds_wfcp[(wpbase + tau0 + i - 9) * 2];
        }
        #pragma unroll
        for (int i = 0; i < 8; ++i) {
            TICK_CORE(tau0 + i, false, xc_[i], wc_[i]);
        }
    }

    // ---- gated tail (ticks 616..618) ----
    for (int tau = TAIL0; tau < NITER; ++tau) {
        const float2 nx = *(const float2*)&lds_x[(tau + 1) * 2];
        const float2 wv = *(const float2*)&lds_wfcp[(wpbase + tau - 9) * 2];
        TICK_CORE(tau, true, nx, wv);
    }
    #undef TICK_CORE

    // layer-4, j2=0 quad (lanes 32-35) writes the outputs
    if (lane >= 32 && lane < 36) {
        out[b * 5 + k] = acc2[0] + b_fc[k];
        if (k == 0) out[b * 5 + 4] = acc2[1] + b_fc[4];
    }
}

extern "C" void kernel_launch(void* const* d_in, const int* in_sizes, int n_in,
                              void* d_out, int out_size, void* d_ws, size_t ws_size,
                              hipStream_t stream)
{
    const float* x     = (const float*)d_in[0];
    const float* w_ih0 = (const float*)d_in[1];
    const float* w_ih  = (const float*)d_in[2];
    const float* w_hh  = (const float*)d_in[3];
    const float* b_ih  = (const float*)d_in[4];
    const float* b_hh  = (const float*)d_in[5];
    const float* w_lin = (const float*)d_in[6];
    const float* b_lin = (const float*)d_in[7];
    const float* w_fc  = (const float*)d_in[8];
    const float* b_fc  = (const float*)d_in[9];
    float* out = (float*)d_out;

    lstm_bp_kernel<<<dim3(BATCH), dim3(64), 0, stream>>>(
        x, w_ih0, w_ih, w_hh, b_ih, b_hh, w_lin, b_lin, w_fc, b_fc, out);
}